// Round 5
// baseline (203.053 us; speedup 1.0000x reference)
//
#include <hip/hip_runtime.h>

// Problem constants (from reference)
#define B_ 32
#define S_ 512
#define H_ 768
#define C_ 32      // N_COLS
#define L_ 16      // MAX_HLEN
#define VOCAB_ 30522

typedef float f4 __attribute__((ext_vector_type(4)));   // native vector: works with nontemporal builtins

__device__ __forceinline__ f4 ld4(const float* p) {
    return *reinterpret_cast<const f4*>(p);
}

// ---------------------------------------------------------------------------
// Kernel 1: pooled[b,c,:] = mean over header_ids[b,c,0:len] of word_emb rows.
// One wave per (b,c): 1024 waves = 256 blocks x 4 waves. hlen==0 rows are
// never read downstream (reference masks them), so we skip them.
// ---------------------------------------------------------------------------
__global__ __launch_bounds__(256) void pool_kernel(
    const int* __restrict__ header_ids,   // [B,C,L]
    const int* __restrict__ header_len,   // [B,C]
    const float* __restrict__ word_emb,   // [VOCAB,H]
    float* __restrict__ pooled)           // [B*C,H] in d_ws
{
    const int wi   = blockIdx.x * 4 + (threadIdx.x >> 6);  // 0..1023 = b*32+c
    const int lane = threadIdx.x & 63;
    const int hlen = header_len[wi];                       // wave-uniform
    if (hlen <= 0) return;

    const int h = lane << 2;
    const int* hid = header_ids + wi * L_;
    f4 a0 = {0,0,0,0}, a1 = {0,0,0,0}, a2 = {0,0,0,0};
    for (int l = 0; l < hlen; ++l) {
        const float* r = word_emb + (size_t)hid[l] * H_ + h;
        a0 += ld4(r);
        a1 += ld4(r + 256);
        a2 += ld4(r + 512);
    }
    const float inv = 1.0f / (float)hlen;
    float* o = pooled + (size_t)wi * H_ + h;
    *reinterpret_cast<f4*>(o)       = a0 * inv;
    *reinterpret_cast<f4*>(o + 256) = a1 * inv;
    *reinterpret_cast<f4*>(o + 512) = a2 * inv;
}

// ---------------------------------------------------------------------------
// Kernel 2: per-token uniform work — pick word row (word_emb or pooled),
// add 4 aux embeddings, TF LayerNorm, store. One wave per token, no barrier.
// ---------------------------------------------------------------------------
__global__ __launch_bounds__(256) void bert_emb_kernel(
    const int* __restrict__ input_ids,       // [B,S]
    const int* __restrict__ token_type_ids,  // [B,S]
    const int* __restrict__ match_type_ids,  // [B,S]
    const int* __restrict__ type_idx,        // [B,S]
    const int* __restrict__ col_pos,         // [B,C]
    const int* __restrict__ col_idx,         // [B,C]
    const int* __restrict__ header_len,      // [B,C]
    const float* __restrict__ word_emb,      // [VOCAB,H]
    const float* __restrict__ pos_emb,       // [MAX_POS,H]
    const float* __restrict__ tok_type_emb,  // [2,H]
    const float* __restrict__ match_emb,     // [11,H]
    const float* __restrict__ type_emb,      // [6,H]
    const float* __restrict__ ln_w,          // [H]
    const float* __restrict__ ln_b,          // [H]
    const float* __restrict__ pooled,        // [B*C,H] from kernel 1
    float* __restrict__ out)                 // [B,S,H]
{
    const int tok  = blockIdx.x * 4 + (threadIdx.x >> 6);  // 0..16383
    const int lane = threadIdx.x & 63;
    const int b    = tok >> 9;
    const int s    = tok & (S_ - 1);

    // override check: one ballot over the low 32 lanes
    const int cp = col_pos[(b << 5) + (lane & 31)];
    unsigned long long m = __ballot(cp == s) & 0xffffffffULL;
    const float* wrow;
    if (m) {
        const int cm = __ffsll(m) - 1;             // col_pos distinct per row
        const int ci = col_idx[(b << 5) + cm];
        if (header_len[(b << 5) + ci] > 0)
            wrow = pooled + (size_t)((b << 5) + ci) * H_;
        else
            wrow = word_emb + (size_t)input_ids[tok] * H_;
    } else {
        wrow = word_emb + (size_t)input_ids[tok] * H_;
    }

    const int h = lane << 2;   // lane owns h, h+256, h+512 (3 x float4)
    f4 a0 = ld4(wrow + h);
    f4 a1 = ld4(wrow + h + 256);
    f4 a2 = ld4(wrow + h + 512);
    {
        const float* r = pos_emb + s * H_ + h;
        a0 += ld4(r); a1 += ld4(r + 256); a2 += ld4(r + 512);
    }
    {
        const float* r = tok_type_emb + token_type_ids[tok] * H_ + h;
        a0 += ld4(r); a1 += ld4(r + 256); a2 += ld4(r + 512);
    }
    {
        const float* r = match_emb + match_type_ids[tok] * H_ + h;
        a0 += ld4(r); a1 += ld4(r + 256); a2 += ld4(r + 512);
    }
    {
        const float* r = type_emb + type_idx[tok] * H_ + h;
        a0 += ld4(r); a1 += ld4(r + 256); a2 += ld4(r + 512);
    }

    // LayerNorm: wave butterfly reduce (all lanes end with totals)
    float s1 = a0.x+a0.y+a0.z+a0.w + a1.x+a1.y+a1.z+a1.w + a2.x+a2.y+a2.z+a2.w;
    float s2 = a0.x*a0.x+a0.y*a0.y+a0.z*a0.z+a0.w*a0.w
             + a1.x*a1.x+a1.y*a1.y+a1.z*a1.z+a1.w*a1.w
             + a2.x*a2.x+a2.y*a2.y+a2.z*a2.z+a2.w*a2.w;
    #pragma unroll
    for (int off = 32; off > 0; off >>= 1) {
        s1 += __shfl_xor(s1, off);
        s2 += __shfl_xor(s2, off);
    }
    const float mean = s1 * (1.0f / H_);
    float var = fmaxf(s2 * (1.0f / H_) - mean * mean, 0.0f);
    const float rstd = rsqrtf(var + 1e-12f);

    // scale/shift, non-temporal store (output never re-read; keep L2 for gathers)
    float* op = out + (size_t)tok * H_ + h;
    {
        f4 w = ld4(ln_w + h), c = ld4(ln_b + h);
        f4 o = (a0 - mean) * rstd * w + c;
        __builtin_nontemporal_store(o, reinterpret_cast<f4*>(op));
    }
    {
        f4 w = ld4(ln_w + h + 256), c = ld4(ln_b + h + 256);
        f4 o = (a1 - mean) * rstd * w + c;
        __builtin_nontemporal_store(o, reinterpret_cast<f4*>(op + 256));
    }
    {
        f4 w = ld4(ln_w + h + 512), c = ld4(ln_b + h + 512);
        f4 o = (a2 - mean) * rstd * w + c;
        __builtin_nontemporal_store(o, reinterpret_cast<f4*>(op + 512));
    }
}

extern "C" void kernel_launch(void* const* d_in, const int* in_sizes, int n_in,
                              void* d_out, int out_size, void* d_ws, size_t ws_size,
                              hipStream_t stream) {
    const int* input_ids      = (const int*)d_in[0];
    const int* header_ids     = (const int*)d_in[1];
    const int* token_type_ids = (const int*)d_in[2];
    const int* match_type_ids = (const int*)d_in[3];
    const int* type_idx       = (const int*)d_in[4];
    const int* col_pos        = (const int*)d_in[5];
    const int* col_idx        = (const int*)d_in[6];
    const int* header_len     = (const int*)d_in[7];
    const float* word_emb     = (const float*)d_in[8];
    const float* pos_emb      = (const float*)d_in[9];
    const float* tok_type_emb = (const float*)d_in[10];
    const float* match_emb    = (const float*)d_in[11];
    const float* type_emb     = (const float*)d_in[12];
    const float* ln_w         = (const float*)d_in[13];
    const float* ln_b         = (const float*)d_in[14];
    float* out    = (float*)d_out;
    float* pooled = (float*)d_ws;   // B*C*H floats = 3.1 MB

    pool_kernel<<<(B_ * C_) / 4, 256, 0, stream>>>(
        header_ids, header_len, word_emb, pooled);

    bert_emb_kernel<<<(B_ * S_) / 4, 256, 0, stream>>>(
        input_ids, token_type_ids, match_type_ids, type_idx,
        col_pos, col_idx, header_len, word_emb, pos_emb, tok_type_emb,
        match_emb, type_emb, ln_w, ln_b, pooled, out);
}

// Round 6
// 191.009 us; speedup vs baseline: 1.0631x; 1.0631x over previous
//
#include <hip/hip_runtime.h>

// Problem constants (from reference)
#define B_ 32
#define S_ 512
#define H_ 768
#define C_ 32      // N_COLS
#define L_ 16      // MAX_HLEN

typedef float f4 __attribute__((ext_vector_type(4)));  // native vector (nontemporal-store capable)

__device__ __forceinline__ f4 ld4(const float* p) {
    return *reinterpret_cast<const f4*>(p);
}

// One WAVE (64 lanes) per token; 12 floats per lane (3 x float4 chunks of 256).
// 256-thread blocks = 4 waves = 4 tokens per block -> grid = B*S/4 = 4096.
// Single dispatch, no __syncthreads: LayerNorm reduce is a wave shfl_xor butterfly.
__global__ __launch_bounds__(256) void bert_emb_kernel(
    const int* __restrict__ input_ids,       // [B,S]
    const int* __restrict__ header_ids,      // [B,C,L]
    const int* __restrict__ token_type_ids,  // [B,S]
    const int* __restrict__ match_type_ids,  // [B,S]
    const int* __restrict__ type_idx,        // [B,S]
    const int* __restrict__ col_pos,         // [B,C]
    const int* __restrict__ col_idx,         // [B,C]
    const int* __restrict__ header_len,      // [B,C]
    const float* __restrict__ word_emb,      // [VOCAB,H] f32
    const float* __restrict__ pos_emb,       // [MAX_POS,H]
    const float* __restrict__ tok_type_emb,  // [2,H]
    const float* __restrict__ match_emb,     // [11,H]
    const float* __restrict__ type_emb,      // [6,H]
    const float* __restrict__ ln_w,          // [H]
    const float* __restrict__ ln_b,          // [H]
    float* __restrict__ out)                 // [B,S,H] f32
{
    const int tok  = blockIdx.x * 4 + (threadIdx.x >> 6);  // 0..16383
    const int lane = threadIdx.x & 63;
    const int b    = tok >> 9;
    const int s    = tok & (S_ - 1);

    // ---- override check: one ballot over the low 32 lanes (col_pos distinct per row)
    const int cp = col_pos[(b << 5) + (lane & 31)];
    unsigned long long m = __ballot(cp == s) & 0xffffffffULL;
    int use_pool = 0, ci = 0, hlen = 0;
    if (m) {
        const int cm = __ffsll(m) - 1;
        ci   = col_idx[(b << 5) + cm];
        hlen = header_len[(b << 5) + ci];
        use_pool = (hlen > 0);
    }

    const int h = lane << 2;   // lane owns h, h+256, h+512 (3 x float4)
    f4 a0, a1, a2;

    // ---- word vector: gather (common) or variable-length mean pool (2/32 tokens; wave-uniform)
    if (use_pool) {
        a0 = (f4){0,0,0,0}; a1 = (f4){0,0,0,0}; a2 = (f4){0,0,0,0};
        const int* hid = header_ids + ((b << 5) + ci) * L_;
        for (int l = 0; l < hlen; ++l) {
            const float* r = word_emb + (size_t)hid[l] * H_ + h;
            a0 += ld4(r); a1 += ld4(r + 256); a2 += ld4(r + 512);
        }
        const float inv = 1.0f / (float)hlen;
        a0 *= inv; a1 *= inv; a2 *= inv;
    } else {
        const float* r = word_emb + (size_t)input_ids[tok] * H_ + h;
        a0 = ld4(r); a1 = ld4(r + 256); a2 = ld4(r + 512);
    }

    // ---- add the four auxiliary embeddings (independent loads -> deep ILP)
    {
        const float* r = pos_emb + s * H_ + h;
        a0 += ld4(r); a1 += ld4(r + 256); a2 += ld4(r + 512);
    }
    {
        const float* r = tok_type_emb + token_type_ids[tok] * H_ + h;
        a0 += ld4(r); a1 += ld4(r + 256); a2 += ld4(r + 512);
    }
    {
        const float* r = match_emb + match_type_ids[tok] * H_ + h;
        a0 += ld4(r); a1 += ld4(r + 256); a2 += ld4(r + 512);
    }
    {
        const float* r = type_emb + type_idx[tok] * H_ + h;
        a0 += ld4(r); a1 += ld4(r + 256); a2 += ld4(r + 512);
    }

    // ---- LayerNorm over H=768: wave butterfly (all lanes end with totals)
    float s1 = a0.x+a0.y+a0.z+a0.w + a1.x+a1.y+a1.z+a1.w + a2.x+a2.y+a2.z+a2.w;
    float s2 = a0.x*a0.x+a0.y*a0.y+a0.z*a0.z+a0.w*a0.w
             + a1.x*a1.x+a1.y*a1.y+a1.z*a1.z+a1.w*a1.w
             + a2.x*a2.x+a2.y*a2.y+a2.z*a2.z+a2.w*a2.w;
    #pragma unroll
    for (int off = 32; off > 0; off >>= 1) {
        s1 += __shfl_xor(s1, off);
        s2 += __shfl_xor(s2, off);
    }
    const float mean = s1 * (1.0f / H_);
    float var = fmaxf(s2 * (1.0f / H_) - mean * mean, 0.0f);
    const float rstd = rsqrtf(var + 1e-12f);

    // ---- scale/shift, non-temporal store (output never re-read; keep L2/L3 for gathers)
    float* op = out + (size_t)tok * H_ + h;
    {
        f4 w = ld4(ln_w + h), c = ld4(ln_b + h);
        f4 o = (a0 - mean) * rstd * w + c;
        __builtin_nontemporal_store(o, reinterpret_cast<f4*>(op));
    }
    {
        f4 w = ld4(ln_w + h + 256), c = ld4(ln_b + h + 256);
        f4 o = (a1 - mean) * rstd * w + c;
        __builtin_nontemporal_store(o, reinterpret_cast<f4*>(op + 256));
    }
    {
        f4 w = ld4(ln_w + h + 512), c = ld4(ln_b + h + 512);
        f4 o = (a2 - mean) * rstd * w + c;
        __builtin_nontemporal_store(o, reinterpret_cast<f4*>(op + 512));
    }
}

extern "C" void kernel_launch(void* const* d_in, const int* in_sizes, int n_in,
                              void* d_out, int out_size, void* d_ws, size_t ws_size,
                              hipStream_t stream) {
    const int* input_ids      = (const int*)d_in[0];
    const int* header_ids     = (const int*)d_in[1];
    const int* token_type_ids = (const int*)d_in[2];
    const int* match_type_ids = (const int*)d_in[3];
    const int* type_idx       = (const int*)d_in[4];
    const int* col_pos        = (const int*)d_in[5];
    const int* col_idx        = (const int*)d_in[6];
    const int* header_len     = (const int*)d_in[7];
    const float* word_emb     = (const float*)d_in[8];
    const float* pos_emb      = (const float*)d_in[9];
    const float* tok_type_emb = (const float*)d_in[10];
    const float* match_emb    = (const float*)d_in[11];
    const float* type_emb     = (const float*)d_in[12];
    const float* ln_w         = (const float*)d_in[13];
    const float* ln_b         = (const float*)d_in[14];
    float* out = (float*)d_out;

    bert_emb_kernel<<<(B_ * S_) / 4, 256, 0, stream>>>(
        input_ids, header_ids, token_type_ids, match_type_ids, type_idx,
        col_pos, col_idx, header_len, word_emb, pos_emb, tok_type_emb,
        match_emb, type_emb, ln_w, ln_b, out);
}